// Round 2
// baseline (2838.736 us; speedup 1.0000x reference)
//
#include <hip/hip_runtime.h>
#include <math.h>

// ---------------- dims / constants ----------------
#define EPS_Q 1e-4
#define TOLC  1e-3

// ws layout: doubles first
#define OFF_D22   0        // [32][32]
#define OFF_RINV  1024     // [32][32]
#define OFF_VR    2048     // [160][32]
#define OFF_T1    7168     // [160][32]
#define OFF_H     12288    // [160][160]
#define OFF_E     37888    // [64][64]
#define OFF_EI    41984    // [64][64]
#define OFF_TMP   46080    // [64][64]
#define OFF_TMP2  50176    // [64][64]
#define D_END     54272    // doubles
// float blob appended after doubles (byte offset D_END*8 = 434176, 16B aligned)
// F_WXT  = 0      : Wx k-major f4-transposed [32 chunks][64 rows][4] = 8192 floats
// F_WYT  = 8192   : Wy k-major f4-transposed [32 chunks][32 rows][4] = 4096 floats
// F_D11  = 12288  : [32][32] strictly-lower, pre-scaled by 1/Lam_i   = 1024
// F_WA   = 13312  : [32][96] rows [C1(64)|D12(32)] * (1/Lam_r)        = 3072

// ================= prep 1: D22, R_cal^-1, vec_r, T1 =================
__global__ __launch_bounds__(256, 1) void prep1(
    const float* __restrict__ B2, const float* __restrict__ C2,
    const float* __restrict__ D12, const float* __restrict__ L,
    const float* __restrict__ U, const float* __restrict__ D21,
    const float* __restrict__ gam, double* __restrict__ wsd)
{
  __shared__ double aug[32][65];
  __shared__ double sFac[32];
  __shared__ int sPiv;
  const int tid = threadIdx.x;
  const double g = (double)gam[0];
  double* D22d = wsd + OFF_D22;

  // D22 = (g+1) I + L^T L + (U - U^T)
  for (int idx = tid; idx < 1024; idx += 256) {
    int i = idx >> 5, j = idx & 31;
    double s = (i == j) ? (g + 1.0) : 0.0;
    for (int k = 0; k < 32; ++k) s += (double)L[k*32+i] * (double)L[k*32+j];
    s += (double)U[i*32+j] - (double)U[j*32+i];
    D22d[idx] = s;
  }
  __syncthreads();
  // R_cal = -2g I + D22 + D22^T - eps * D22^T D22  -> aug left; I -> aug right
  for (int idx = tid; idx < 1024; idx += 256) {
    int i = idx >> 5, j = idx & 31;
    double s = (i == j) ? (-2.0 * g) : 0.0;
    s += D22d[i*32+j] + D22d[j*32+i];
    double q = 0.0;
    for (int k = 0; k < 32; ++k) q += D22d[k*32+i] * D22d[k*32+j];
    aug[i][j] = s - EPS_Q * q;
    aug[i][32+j] = (i == j) ? 1.0 : 0.0;
  }
  __syncthreads();
  // Gauss-Jordan with partial pivoting (32x64)
  for (int k = 0; k < 32; ++k) {
    if (tid == 0) {
      int p = k; double best = fabs(aug[k][k]);
      for (int r = k+1; r < 32; ++r) { double v = fabs(aug[r][k]); if (v > best) { best = v; p = r; } }
      sPiv = p;
    }
    __syncthreads();
    int p = sPiv;
    if (p != k) for (int c = tid; c < 64; c += 256) { double t1 = aug[k][c]; aug[k][c] = aug[p][c]; aug[p][c] = t1; }
    __syncthreads();
    double pinv = 1.0 / aug[k][k];
    __syncthreads();
    for (int c = tid; c < 64; c += 256) aug[k][c] *= pinv;
    __syncthreads();
    if (tid < 32) sFac[tid] = aug[tid][k];
    __syncthreads();
    for (int idx = tid; idx < 2048; idx += 256) {
      int r = idx >> 6, c = idx & 63;
      if (r != k) aug[r][c] -= sFac[r] * aug[k][c];
    }
    __syncthreads();
  }
  double* Rinv = wsd + OFF_RINV;
  for (int idx = tid; idx < 1024; idx += 256) Rinv[idx] = aug[idx >> 5][32 + (idx & 31)];

  // vec_r rows: [C2_cal^T (64) ; D21_cal^T (32) ; B2 (64)], M = I - eps*D22^T
  double* vr = wsd + OFF_VR;
  for (int idx = tid; idx < 64*32; idx += 256) {        // C2_cal^T
    int p = idx >> 5, k = idx & 31;
    double q = 0.0;
    for (int m = 0; m < 32; ++m) q += D22d[m*32+k] * (double)C2[m*64+p];
    vr[p*32+k] = (double)C2[k*64+p] - EPS_Q * q;
  }
  for (int idx = tid; idx < 32*32; idx += 256) {        // D21_cal^T
    int p = idx >> 5, k = idx & 31;
    double q = 0.0;
    for (int m = 0; m < 32; ++m) q += D22d[m*32+k] * (double)D21[m*32+p];
    vr[(64+p)*32+k] = (double)D21[k*32+p] - EPS_Q * q - (double)D12[p*32+k];
  }
  for (int idx = tid; idx < 64*32; idx += 256) {        // B2
    int p = idx >> 5, k = idx & 31;
    vr[(96+p)*32+k] = (double)B2[p*32+k];
  }
  __syncthreads();
  // T1 = vec_r @ Rinv  (160x32)
  double* T1 = wsd + OFF_T1;
  for (int idx = tid; idx < 160*32; idx += 256) {
    int p = idx >> 5, k2 = idx & 31;
    double s = 0.0;
    for (int k = 0; k < 32; ++k) s += vr[p*32+k] * Rinv[k*32+k2];
    T1[idx] = s;
  }
}

// ================= prep 2: H = X^T X + tol I + psi_r - psi_q =================
__global__ __launch_bounds__(256, 1) void prep2(
    const float* __restrict__ X, const float* __restrict__ C2,
    const float* __restrict__ D21, double* __restrict__ wsd)
{
  const double* vr = wsd + OFF_VR;
  const double* T1 = wsd + OFF_T1;
  double* H = wsd + OFF_H;
  int bi = blockIdx.x / 10, bj = blockIdx.x % 10;
  int i = bi*16 + (threadIdx.x >> 4);
  int j = bj*16 + (threadIdx.x & 15);
  double s = (i == j) ? TOLC : 0.0;
  for (int k = 0; k < 160; ++k) s += (double)X[k*160+i] * (double)X[k*160+j];
  double pr = 0.0;
  for (int k = 0; k < 32; ++k) pr += T1[i*32+k] * vr[j*32+k];
  s += pr;
  if (i < 96 && j < 96) {
    double vq = 0.0;
    for (int k = 0; k < 32; ++k) {
      double a = (i < 64) ? (double)C2[k*64+i] : (double)D21[k*32+(i-64)];
      double b = (j < 64) ? (double)C2[k*64+j] : (double)D21[k*32+(j-64)];
      vq += a*b;
    }
    s += EPS_Q * vq;
  }
  H[i*160+j] = s;
}

// ================= prep 3: E^-1 (GJ fp32 + 2x fp64 Newton), weight blob =================
__global__ __launch_bounds__(256, 1) void prep3(
    const float* __restrict__ Y, const float* __restrict__ B2,
    const float* __restrict__ C2, const float* __restrict__ D12,
    const float* __restrict__ D21, double* __restrict__ wsd)
{
  __shared__ float aug[64][130];
  __shared__ float sFac[64];
  __shared__ int sPiv;
  const int tid = threadIdx.x;
  double* H   = wsd + OFF_H;
  double* Ed  = wsd + OFF_E;
  double* Ei  = wsd + OFF_EI;
  double* Tm  = wsd + OFF_TMP;
  double* Tm2 = wsd + OFF_TMP2;
  double* D22d = wsd + OFF_D22;
  float* fb = (float*)(wsd + D_END);

  // E = 0.5*(H11 + H33 + Y - Y^T)
  for (int idx = tid; idx < 4096; idx += 256) {
    int i = idx >> 6, j = idx & 63;
    double e = 0.5*(H[i*160+j] + H[(96+i)*160+(96+j)] + (double)Y[i*64+j] - (double)Y[j*64+i]);
    Ed[idx] = e;
    aug[i][j] = (float)e;
    aug[i][64+j] = (i == j) ? 1.f : 0.f;
  }
  __syncthreads();
  for (int k = 0; k < 64; ++k) {
    if (tid == 0) {
      int p = k; float best = fabsf(aug[k][k]);
      for (int r = k+1; r < 64; ++r) { float v = fabsf(aug[r][k]); if (v > best) { best = v; p = r; } }
      sPiv = p;
    }
    __syncthreads();
    int p = sPiv;
    if (p != k) for (int c = tid; c < 128; c += 256) { float t1 = aug[k][c]; aug[k][c] = aug[p][c]; aug[p][c] = t1; }
    __syncthreads();
    float pinv = 1.0f / aug[k][k];
    __syncthreads();
    for (int c = tid; c < 128; c += 256) aug[k][c] *= pinv;
    __syncthreads();
    if (tid < 64) sFac[tid] = aug[tid][k];
    __syncthreads();
    for (int idx = tid; idx < 64*128; idx += 256) {
      int r = idx >> 7, c = idx & 127;
      if (r != k) aug[r][c] -= sFac[r] * aug[k][c];
    }
    __syncthreads();
  }
  for (int idx = tid; idx < 4096; idx += 256) Ei[idx] = (double)aug[idx >> 6][64 + (idx & 63)];
  __syncthreads();
  // Newton refinement x2: Ei <- Ei (2I - Ed Ei)
  for (int it = 0; it < 2; ++it) {
    for (int idx = tid; idx < 4096; idx += 256) {
      int i = idx >> 6, j = idx & 63;
      double s = (i == j) ? 2.0 : 0.0;
      for (int k = 0; k < 64; ++k) s -= Ed[i*64+k] * Ei[k*64+j];
      Tm[idx] = s;
    }
    __syncthreads();
    for (int idx = tid; idx < 4096; idx += 256) {
      int i = idx >> 6, j = idx & 63;
      double s = 0.0;
      for (int k = 0; k < 64; ++k) s += Ei[i*64+k] * Tm[k*64+j];
      Tm2[idx] = s;
    }
    __syncthreads();
    for (int idx = tid; idx < 4096; idx += 256) Ei[idx] = Tm2[idx];
    __syncthreads();
  }
  // WxT: k-major f4-transposed [32 chunks][64 rows][4]
  // cols of Wx row r: [A1(64) | A2(32) | A3(32)] = Ei @ [Fm | B1 | B2]
  for (int idx = tid; idx < 64*128; idx += 256) {
    int r = idx >> 7, col = idx & 127;
    double s = 0.0;
    if (col < 64)       { for (int k = 0; k < 64; ++k) s += Ei[r*64+k] * H[(96+k)*160 + col]; }
    else if (col < 96)  { int jj = col-64; for (int k = 0; k < 64; ++k) s += Ei[r*64+k] * H[(96+k)*160 + 64 + jj]; }
    else                { int jj = col-96; for (int k = 0; k < 64; ++k) s += Ei[r*64+k] * (double)B2[k*32+jj]; }
    fb[((col >> 2)*64 + r)*4 + (col & 3)] = (float)s;
  }
  // WyT: k-major f4-transposed [32 chunks][32 rows][4]; cols [C2(64)|D21(32)|D22(32)]
  for (int idx = tid; idx < 32*128; idx += 256) {
    int r = idx >> 7, col = idx & 127;
    float v;
    if (col < 64)      v = C2[r*64 + col];
    else if (col < 96) v = D21[r*32 + (col-64)];
    else               v = (float)D22d[r*32 + (col-96)];
    fb[8192 + ((col >> 2)*32 + r)*4 + (col & 3)] = v;
  }
  // D11' (strict lower, scaled by 1/Lam_i) @ 12288
  for (int idx = tid; idx < 1024; idx += 256) {
    int i = idx >> 5, j = idx & 31;
    double li = 2.0 / H[(64+i)*160 + 64+i];
    fb[12288 + idx] = (j < i) ? (float)(-H[(64+i)*160 + 64+j] * li) : 0.f;
  }
  // Wa = [C1 | D12] * (1/Lam_r), row-major [32][96] @ 13312
  for (int idx = tid; idx < 32*96; idx += 256) {
    int r = idx / 96, j = idx % 96;
    double li = 2.0 / H[(64+r)*160 + 64+r];
    double v = (j < 64) ? (-H[(64+r)*160 + j] * li) : ((double)D12[r*32 + (j-64)] * li);
    fb[13312 + idx] = (float)v;
  }
}

// ================= main recurrence =================
__device__ __forceinline__ float frcp(float x) {
#if __has_builtin(__builtin_amdgcn_rcpf)
  return __builtin_amdgcn_rcpf(x);
#else
  return 1.0f / x;
#endif
}
__device__ __forceinline__ float ftanh(float x) {
  float xc = fminf(fmaxf(x, -15.f), 15.f);
  float E = __builtin_exp2f(xc * 2.8853900817779268f);  // e^{2x}
  return 1.f - 2.f * frcp(E + 1.f);
}

// block = 256 threads = 4 elements; grid = 512 (2 blocks/CU, 8 waves/CU)
// LDS: WxT 32 KiB + WyT 16 KiB + D11 4 KiB + xb 4.2 KiB = 57.4 KiB
__global__ __launch_bounds__(256, 2) void ren_main(
    const float* __restrict__ u_in, const float* __restrict__ x0,
    const double* __restrict__ wsd, float* __restrict__ out)
{
  __shared__ __align__(16) float sWxT[8192];   // [32 chunks][64 rows] f4
  __shared__ __align__(16) float sWyT[4096];   // [32 chunks][32 rows] f4
  __shared__ __align__(16) float sD11[1024];   // [32][8] f4
  __shared__ __align__(16) float xb[2][528];   // per-elem stride 132: [x(64)|a/w(32)|u(32)|pad]
  const float* fb = (const float*)(wsd + D_END);
  const int tid = threadIdx.x;
  // stage weights
  {
    const float4* g = (const float4*)fb;
    float4* s1 = (float4*)sWxT;
    for (int i = tid; i < 2048; i += 256) s1[i] = g[i];
    float4* s2 = (float4*)sWyT;
    for (int i = tid; i < 1024; i += 256) s2[i] = g[2048 + i];
    float4* s3 = (float4*)sD11;
    if (tid < 256) s3[tid] = g[3072 + tid];
  }
  // phase mappings
  const int eX = tid & 3, rX = tid >> 2;                 // X: 4 elems x 64 rows
  const int eA = tid & 3, hA = (tid >> 2) & 1, rA = tid >> 3; // A,Y: 4 x 2 x 32
  const int b = blockIdx.x * 4;
  const float* uX = u_in + (size_t)(b + eX) * 8192;
  float* outA = out + (size_t)(b + eA) * 8192;
  const float4* Wa4  = (const float4*)(fb + 13312);      // global, L1-resident
  const float4* WxT4 = (const float4*)sWxT;
  const float4* WyT4 = (const float4*)sWyT;
  const float4* D114 = (const float4*)sD11;
  float*  xf  = &xb[0][0];
  float4* xb4 = (float4*)xf;                             // [2][132] f4
  // prologue: x0 and u(t=0)
  {
    int e = tid >> 6, c = tid & 63;
    xf[e*132 + c] = x0[(b + e)*64 + c];
    if (tid < 128) {
      int e2 = tid >> 5, c2 = tid & 31;
      xf[e2*132 + 96 + c2] = u_in[(size_t)(b + e2)*8192 + c2];
    }
  }
  __syncthreads();

  for (int t = 0; t < 256; ++t) {
    const int p = t & 1, q = p ^ 1;
    // u prefetch for next step (X-mapping lanes rX<32)
    float upre = 0.f;
    if (rX < 32) {
      int tn = (t < 255) ? (t + 1) : 255;
      upre = uX[tn*32 + rX];
    }
    // ---- phase A: a_r = (Wa . [x;u])_r, split over hA ----
    {
      float4 acc = make_float4(0.f, 0.f, 0.f, 0.f);
      #pragma unroll
      for (int c = 0; c < 12; ++c) {
        int ch = hA*12 + c;
        float4 wv = Wa4[rA*24 + ch];
        int xi = (ch < 16) ? ch : (ch + 8);   // u chunks live at f4 24..31
        float4 xv = xb4[p*132 + eA*33 + xi];
        acc.x += wv.x*xv.x; acc.y += wv.y*xv.y; acc.z += wv.z*xv.z; acc.w += wv.w*xv.w;
      }
      float a = (acc.x + acc.y) + (acc.z + acc.w);
      a += __shfl_xor(a, 4);
      if (hA == 0) xf[p*528 + eA*132 + 64 + rA] = a;
    }
    __syncthreads();                                     // B1
    // ---- w phase: waves 0,1; wave halves = elements ----
    if (tid < 128) {
      const int m = tid >> 5;                            // element 0..3
      const int j = tid & 31;
      const int base = p*528 + m*132 + 64;               // a/w slot
      float w[32];
      #pragma unroll
      for (int i2 = 0; i2 < 32; ++i2) w[i2] = 0.f;
      #pragma unroll
      for (int i = 0; i < 32; ++i) {
        float v = xf[base + i];                          // a_i (broadcast)
        const int nch = (i + 3) >> 2;
        #pragma unroll
        for (int jj = 0; jj < 8; ++jj) {
          if (jj < nch) {
            float4 d = D114[i*8 + jj];
            v += d.x*w[4*jj] + d.y*w[4*jj+1] + d.z*w[4*jj+2] + d.w*w[4*jj+3];
          }
        }
        w[i] = ftanh(v);
      }
      xf[base + j] = w[j];
    }
    __syncthreads();                                     // B2
    // ---- phase X: xn_r = (Wx . [x;w;u])_r  (one row per lane) ----
    {
      float4 acc = make_float4(0.f, 0.f, 0.f, 0.f);
      #pragma unroll
      for (int j = 0; j < 32; ++j) {
        float4 wv = WxT4[j*64 + rX];
        float4 xv = xb4[p*132 + eX*33 + j];
        acc.x += wv.x*xv.x; acc.y += wv.y*xv.y; acc.z += wv.z*xv.z; acc.w += wv.w*xv.w;
      }
      float xn = (acc.x + acc.y) + (acc.z + acc.w);
      xf[q*528 + eX*132 + rX] = xn;
      if (rX < 32) xf[q*528 + eX*132 + 96 + rX] = upre;  // u_{t+1}
    }
    __syncthreads();                                     // B3
    // ---- phase Y: y_r = (Wy . [xn;w;u])_r, split over hA ----
    {
      float4 acc = make_float4(0.f, 0.f, 0.f, 0.f);
      #pragma unroll
      for (int c = 0; c < 16; ++c) {
        int ch = hA*16 + c;
        float4 wv = WyT4[ch*32 + rA];
        float4 xv = (hA == 0) ? xb4[q*132 + eA*33 + c]          // xn chunks 0..15
                              : xb4[p*132 + eA*33 + 16 + c];    // [w|u] chunks 16..31
        acc.x += wv.x*xv.x; acc.y += wv.y*xv.y; acc.z += wv.z*xv.z; acc.w += wv.w*xv.w;
      }
      float y = (acc.x + acc.y) + (acc.z + acc.w);
      y += __shfl_xor(y, 4);
      if (hA == 0) outA[t*32 + rA] = y;
    }
    // no barrier needed here: next A only reads xb[q].{x,u} (written before B3)
    // and writes xb[q].w-slot which nothing still reads.
  }
}

// ================= launch =================
extern "C" void kernel_launch(void* const* d_in, const int* in_sizes, int n_in,
                              void* d_out, int out_size, void* d_ws, size_t ws_size,
                              hipStream_t stream)
{
  const float* u_in = (const float*)d_in[0];
  const float* x0   = (const float*)d_in[1];
  const float* X    = (const float*)d_in[2];
  const float* Y    = (const float*)d_in[3];
  const float* B2   = (const float*)d_in[4];
  const float* C2   = (const float*)d_in[5];
  const float* D12  = (const float*)d_in[6];
  const float* L    = (const float*)d_in[7];   // D22_L
  const float* U    = (const float*)d_in[8];   // D22_U
  const float* D21  = (const float*)d_in[9];
  const float* gam  = (const float*)d_in[10];
  double* wsd = (double*)d_ws;
  float* out = (float*)d_out;

  hipLaunchKernelGGL(prep1, dim3(1), dim3(256), 0, stream, B2, C2, D12, L, U, D21, gam, wsd);
  hipLaunchKernelGGL(prep2, dim3(100), dim3(256), 0, stream, X, C2, D21, wsd);
  hipLaunchKernelGGL(prep3, dim3(1), dim3(256), 0, stream, Y, B2, C2, D12, D21, wsd);
  hipLaunchKernelGGL(ren_main, dim3(512), dim3(256), 0, stream, u_in, x0, wsd, out);
}

// Round 3
// 1741.709 us; speedup vs baseline: 1.6299x; 1.6299x over previous
//
#include <hip/hip_runtime.h>
#include <math.h>

// ---------------- dims / constants ----------------
#define EPS_Q 1e-4
#define TOLC  1e-3

// ws layout: doubles first
#define OFF_D22   0        // [32][32]
#define OFF_RINV  1024     // [32][32]
#define OFF_VR    2048     // [160][32]
#define OFF_T1    7168     // [160][32]
#define OFF_H     12288    // [160][160]
#define OFF_E     37888    // [64][64]
#define OFF_EI    41984    // [64][64]
#define OFF_TMP   46080    // [64][64]
#define OFF_TMP2  50176    // [64][64]
#define D_END     54272    // doubles
// float blob after doubles (byte offset 434176, 16B aligned):
// F_WXT  = 0      : Wx k-major f4-transposed [32 chunks][64 rows][4] = 8192 floats
// F_WYT  = 8192   : Wy k-major f4-transposed [32 chunks][32 rows][4] = 4096 floats
// F_D11  = 12288  : [32][32] strictly-lower, pre-scaled by 1/Lam_i   = 1024
// F_WA   = 13312  : [32][96] rows [C1(64)|D12(32)] * (1/Lam_r)        = 3072

// ================= prep 1: D22, R_cal^-1, vec_r, T1 =================
__global__ __launch_bounds__(256, 1) void prep1(
    const float* __restrict__ B2, const float* __restrict__ C2,
    const float* __restrict__ D12, const float* __restrict__ L,
    const float* __restrict__ U, const float* __restrict__ D21,
    const float* __restrict__ gam, double* __restrict__ wsd)
{
  __shared__ double aug[32][65];
  __shared__ double sFac[32];
  __shared__ int sPiv;
  const int tid = threadIdx.x;
  const double g = (double)gam[0];
  double* D22d = wsd + OFF_D22;

  // D22 = (g+1) I + L^T L + (U - U^T)
  for (int idx = tid; idx < 1024; idx += 256) {
    int i = idx >> 5, j = idx & 31;
    double s = (i == j) ? (g + 1.0) : 0.0;
    for (int k = 0; k < 32; ++k) s += (double)L[k*32+i] * (double)L[k*32+j];
    s += (double)U[i*32+j] - (double)U[j*32+i];
    D22d[idx] = s;
  }
  __syncthreads();
  // R_cal = -2g I + D22 + D22^T - eps * D22^T D22
  for (int idx = tid; idx < 1024; idx += 256) {
    int i = idx >> 5, j = idx & 31;
    double s = (i == j) ? (-2.0 * g) : 0.0;
    s += D22d[i*32+j] + D22d[j*32+i];
    double q = 0.0;
    for (int k = 0; k < 32; ++k) q += D22d[k*32+i] * D22d[k*32+j];
    aug[i][j] = s - EPS_Q * q;
    aug[i][32+j] = (i == j) ? 1.0 : 0.0;
  }
  __syncthreads();
  // Gauss-Jordan with partial pivoting; wave-parallel pivot scan
  for (int k = 0; k < 32; ++k) {
    if (tid < 64) {
      float mv = -1.f; int mi = k;
      if (tid < 32 && tid >= k) { mv = (float)fabs(aug[tid][k]); mi = tid; }
      #pragma unroll
      for (int o = 32; o; o >>= 1) {
        float ov = __shfl_xor(mv, o); int oi = __shfl_xor(mi, o);
        if (ov > mv) { mv = ov; mi = oi; }
      }
      if (tid == 0) sPiv = mi;
    }
    __syncthreads();
    int p = sPiv;
    if (p != k) for (int c = tid; c < 64; c += 256) { double t1 = aug[k][c]; aug[k][c] = aug[p][c]; aug[p][c] = t1; }
    __syncthreads();
    double pinv = 1.0 / aug[k][k];
    if (tid < 32 && tid != k) sFac[tid] = aug[tid][k];
    __syncthreads();
    for (int c = tid; c < 64; c += 256) aug[k][c] *= pinv;
    __syncthreads();
    for (int idx = tid; idx < 2048; idx += 256) {
      int r = idx >> 6, c = idx & 63;
      if (r != k) aug[r][c] -= sFac[r] * aug[k][c];
    }
    __syncthreads();
  }
  double* Rinv = wsd + OFF_RINV;
  for (int idx = tid; idx < 1024; idx += 256) Rinv[idx] = aug[idx >> 5][32 + (idx & 31)];

  // vec_r rows: [C2_cal^T (64) ; D21_cal^T (32) ; B2 (64)], M = I - eps*D22^T
  double* vr = wsd + OFF_VR;
  for (int idx = tid; idx < 64*32; idx += 256) {
    int p = idx >> 5, k = idx & 31;
    double q = 0.0;
    for (int m = 0; m < 32; ++m) q += D22d[m*32+k] * (double)C2[m*64+p];
    vr[p*32+k] = (double)C2[k*64+p] - EPS_Q * q;
  }
  for (int idx = tid; idx < 32*32; idx += 256) {
    int p = idx >> 5, k = idx & 31;
    double q = 0.0;
    for (int m = 0; m < 32; ++m) q += D22d[m*32+k] * (double)D21[m*32+p];
    vr[(64+p)*32+k] = (double)D21[k*32+p] - EPS_Q * q - (double)D12[p*32+k];
  }
  for (int idx = tid; idx < 64*32; idx += 256) {
    int p = idx >> 5, k = idx & 31;
    vr[(96+p)*32+k] = (double)B2[p*32+k];
  }
  __syncthreads();
  // T1 = vec_r @ Rinv  (160x32)
  double* T1 = wsd + OFF_T1;
  for (int idx = tid; idx < 160*32; idx += 256) {
    int p = idx >> 5, k2 = idx & 31;
    double s = 0.0;
    for (int k = 0; k < 32; ++k) s += vr[p*32+k] * Rinv[k*32+k2];
    T1[idx] = s;
  }
}

// ================= prep 2: H = X^T X + tol I + psi_r - psi_q =================
__global__ __launch_bounds__(256, 1) void prep2(
    const float* __restrict__ X, const float* __restrict__ C2,
    const float* __restrict__ D21, double* __restrict__ wsd)
{
  const double* vr = wsd + OFF_VR;
  const double* T1 = wsd + OFF_T1;
  double* H = wsd + OFF_H;
  int bi = blockIdx.x / 10, bj = blockIdx.x % 10;
  int i = bi*16 + (threadIdx.x >> 4);
  int j = bj*16 + (threadIdx.x & 15);
  double s = (i == j) ? TOLC : 0.0;
  for (int k = 0; k < 160; ++k) s += (double)X[k*160+i] * (double)X[k*160+j];
  double pr = 0.0;
  for (int k = 0; k < 32; ++k) pr += T1[i*32+k] * vr[j*32+k];
  s += pr;
  if (i < 96 && j < 96) {
    double vq = 0.0;
    for (int k = 0; k < 32; ++k) {
      double a = (i < 64) ? (double)C2[k*64+i] : (double)D21[k*32+(i-64)];
      double b = (j < 64) ? (double)C2[k*64+j] : (double)D21[k*32+(j-64)];
      vq += a*b;
    }
    s += EPS_Q * vq;
  }
  H[i*160+j] = s;
}

// ================= prep 3: E^-1 (GJ fp32 + 2x fp64 Newton), weight blob =================
__global__ __launch_bounds__(256, 1) void prep3(
    const float* __restrict__ Y, const float* __restrict__ B2,
    const float* __restrict__ C2, const float* __restrict__ D12,
    const float* __restrict__ D21, double* __restrict__ wsd)
{
  __shared__ float aug[64][130];
  __shared__ float sFac[64];
  __shared__ int sPiv;
  const int tid = threadIdx.x;
  double* H   = wsd + OFF_H;
  double* Ed  = wsd + OFF_E;
  double* Ei  = wsd + OFF_EI;
  double* Tm  = wsd + OFF_TMP;
  double* Tm2 = wsd + OFF_TMP2;
  double* D22d = wsd + OFF_D22;
  float* fb = (float*)(wsd + D_END);

  // E = 0.5*(H11 + H33 + Y - Y^T)
  for (int idx = tid; idx < 4096; idx += 256) {
    int i = idx >> 6, j = idx & 63;
    double e = 0.5*(H[i*160+j] + H[(96+i)*160+(96+j)] + (double)Y[i*64+j] - (double)Y[j*64+i]);
    Ed[idx] = e;
    aug[i][j] = (float)e;
    aug[i][64+j] = (i == j) ? 1.f : 0.f;
  }
  __syncthreads();
  for (int k = 0; k < 64; ++k) {
    if (tid < 64) {
      float mv = -1.f; int mi = k;
      if (tid >= k) { mv = fabsf(aug[tid][k]); mi = tid; }
      #pragma unroll
      for (int o = 32; o; o >>= 1) {
        float ov = __shfl_xor(mv, o); int oi = __shfl_xor(mi, o);
        if (ov > mv) { mv = ov; mi = oi; }
      }
      if (tid == 0) sPiv = mi;
    }
    __syncthreads();
    int p = sPiv;
    if (p != k) for (int c = tid; c < 128; c += 256) { float t1 = aug[k][c]; aug[k][c] = aug[p][c]; aug[p][c] = t1; }
    __syncthreads();
    float pinv = 1.0f / aug[k][k];
    if (tid < 64 && tid != k) sFac[tid] = aug[tid][k];
    __syncthreads();
    for (int c = tid; c < 128; c += 256) aug[k][c] *= pinv;
    __syncthreads();
    for (int idx = tid; idx < 64*128; idx += 256) {
      int r = idx >> 7, c = idx & 127;
      if (r != k) aug[r][c] -= sFac[r] * aug[k][c];
    }
    __syncthreads();
  }
  for (int idx = tid; idx < 4096; idx += 256) Ei[idx] = (double)aug[idx >> 6][64 + (idx & 63)];
  __syncthreads();
  // Newton refinement x2: Ei <- Ei (2I - Ed Ei)
  for (int it = 0; it < 2; ++it) {
    for (int idx = tid; idx < 4096; idx += 256) {
      int i = idx >> 6, j = idx & 63;
      double s = (i == j) ? 2.0 : 0.0;
      for (int k = 0; k < 64; ++k) s -= Ed[i*64+k] * Ei[k*64+j];
      Tm[idx] = s;
    }
    __syncthreads();
    for (int idx = tid; idx < 4096; idx += 256) {
      int i = idx >> 6, j = idx & 63;
      double s = 0.0;
      for (int k = 0; k < 64; ++k) s += Ei[i*64+k] * Tm[k*64+j];
      Tm2[idx] = s;
    }
    __syncthreads();
    for (int idx = tid; idx < 4096; idx += 256) Ei[idx] = Tm2[idx];
    __syncthreads();
  }
  // WxT: k-major f4-transposed [32 chunks][64 rows][4]
  for (int idx = tid; idx < 64*128; idx += 256) {
    int r = idx >> 7, col = idx & 127;
    double s = 0.0;
    if (col < 64)       { for (int k = 0; k < 64; ++k) s += Ei[r*64+k] * H[(96+k)*160 + col]; }
    else if (col < 96)  { int jj = col-64; for (int k = 0; k < 64; ++k) s += Ei[r*64+k] * H[(96+k)*160 + 64 + jj]; }
    else                { int jj = col-96; for (int k = 0; k < 64; ++k) s += Ei[r*64+k] * (double)B2[k*32+jj]; }
    fb[((col >> 2)*64 + r)*4 + (col & 3)] = (float)s;
  }
  // WyT: k-major f4-transposed [32 chunks][32 rows][4]; cols [C2(64)|D21(32)|D22(32)]
  for (int idx = tid; idx < 32*128; idx += 256) {
    int r = idx >> 7, col = idx & 127;
    float v;
    if (col < 64)      v = C2[r*64 + col];
    else if (col < 96) v = D21[r*32 + (col-64)];
    else               v = (float)D22d[r*32 + (col-96)];
    fb[8192 + ((col >> 2)*32 + r)*4 + (col & 3)] = v;
  }
  // D11' (strict lower, scaled by 1/Lam_i) @ 12288
  for (int idx = tid; idx < 1024; idx += 256) {
    int i = idx >> 5, j = idx & 31;
    double li = 2.0 / H[(64+i)*160 + 64+i];
    fb[12288 + idx] = (j < i) ? (float)(-H[(64+i)*160 + 64+j] * li) : 0.f;
  }
  // Wa = [C1 | D12] * (1/Lam_r), row-major [32][96] @ 13312
  for (int idx = tid; idx < 32*96; idx += 256) {
    int r = idx / 96, j = idx % 96;
    double li = 2.0 / H[(64+r)*160 + 64+r];
    double v = (j < 64) ? (-H[(64+r)*160 + j] * li) : ((double)D12[r*32 + (j-64)] * li);
    fb[13312 + idx] = (float)v;
  }
}

// ================= main recurrence =================
__device__ __forceinline__ float frcp(float x) {
#if __has_builtin(__builtin_amdgcn_rcpf)
  return __builtin_amdgcn_rcpf(x);
#else
  return 1.0f / x;
#endif
}
__device__ __forceinline__ float ftanh(float x) {
  float xc = fminf(fmaxf(x, -15.f), 15.f);
  float E = __builtin_exp2f(xc * 2.8853900817779268f);  // e^{2x}
  return 1.f - 2.f * frcp(E + 1.f);
}

// block = 256 threads = 4 waves; each WAVE owns 2 elements end-to-end.
// NO __syncthreads in the t-loop: all communication is within one wave
// (same-wave LDS ops complete in program order). Weights Wx/Wy shared in
// LDS; Wa row + D11 row live in per-lane registers (keyed by lane&31).
__global__ __launch_bounds__(256, 1) void ren_main(
    const float* __restrict__ u_in, const float* __restrict__ x0,
    const double* __restrict__ wsd, float* __restrict__ out)
{
  __shared__ __align__(16) float sW[12288];    // WxT [32][64]f4 | WyT [32][32]f4
  __shared__ __align__(16) float sXU[4][264];  // per wave: [2 elems][132]: x|w|u|pad
  const float* fb = (const float*)(wsd + D_END);
  const int tid = threadIdx.x;
  {
    const float4* g4 = (const float4*)fb;
    float4* s4 = (float4*)sW;
    for (int i = tid; i < 3072; i += 256) s4[i] = g4[i];
  }
  const int wv = tid >> 6, l = tid & 63;
  const int h = l >> 5, r = l & 31;
  const int e0 = blockIdx.x * 8 + wv * 2;     // this wave's elements: e0, e0+1
  float* xu = &sXU[wv][0];
  // Wa row r (24 f4) and D11 row r (32 f) into registers
  float4 wa[24];
  {
    const float4* WaG = (const float4*)(fb + 13312);
    #pragma unroll
    for (int c = 0; c < 24; ++c) wa[c] = WaG[r*24 + c];
  }
  float d11[32];
  {
    const float4* DG = (const float4*)(fb + 12288);
    #pragma unroll
    for (int c = 0; c < 8; ++c) {
      float4 dv = DG[r*8 + c];
      d11[4*c+0] = dv.x; d11[4*c+1] = dv.y; d11[4*c+2] = dv.z; d11[4*c+3] = dv.w;
    }
  }
  // x0 and u(t=0) into wave-private LDS
  xu[l]       = x0[(size_t)e0*64 + l];
  xu[132 + l] = x0[(size_t)(e0+1)*64 + l];
  xu[h*132 + 96 + r] = u_in[(size_t)(e0+h)*8192 + r];
  __syncthreads();   // weights staged (once, outside t-loop)
  const float4* xu4  = (const float4*)xu;          // elem stride 33 f4
  const float4* WxT4 = (const float4*)sW;
  const float4* WyT4 = (const float4*)(sW + 8192);
  const float* uG = u_in + (size_t)(e0+h)*8192;
  float* oG = out + (size_t)(e0+h)*8192;

  for (int t = 0; t < 256; ++t) {
    const int tn = (t < 255) ? (t + 1) : 255;
    float unext = uG[tn*32 + r];                   // prefetch u_{t+1}
    // ---- A: a_r = (Wa . [x;u])_r for elem h (Wa in regs, x/u broadcast) ----
    float4 s4 = make_float4(0.f, 0.f, 0.f, 0.f);
    #pragma unroll
    for (int c = 0; c < 16; ++c) {                 // x chunks
      float4 xv = xu4[h*33 + c]; float4 wv4 = wa[c];
      s4.x = fmaf(wv4.x, xv.x, s4.x); s4.y = fmaf(wv4.y, xv.y, s4.y);
      s4.z = fmaf(wv4.z, xv.z, s4.z); s4.w = fmaf(wv4.w, xv.w, s4.w);
    }
    #pragma unroll
    for (int c = 0; c < 8; ++c) {                  // u chunks (f4 24..31)
      float4 xv = xu4[h*33 + 24 + c]; float4 wv4 = wa[16 + c];
      s4.x = fmaf(wv4.x, xv.x, s4.x); s4.y = fmaf(wv4.y, xv.y, s4.y);
      s4.z = fmaf(wv4.z, xv.z, s4.z); s4.w = fmaf(wv4.w, xv.w, s4.w);
    }
    float v = (s4.x + s4.y) + (s4.z + s4.w);
    // ---- w chain: LDS-free; broadcast via readlane (D11 strict-lower zeros
    //      make masking unnecessary; lane's v is final after iter r) ----
    #pragma unroll
    for (int j = 0; j < 31; ++j) {
      float tt = ftanh(v);
      float b0 = __int_as_float(__builtin_amdgcn_readlane(__float_as_int(tt), j));
      float b1 = __int_as_float(__builtin_amdgcn_readlane(__float_as_int(tt), j + 32));
      v = fmaf(d11[j], h ? b1 : b0, v);
    }
    float myw = ftanh(v);
    xu[h*132 + 64 + r] = myw;                      // publish w to wave LDS
    // ---- X: x_new rows, lane = row l, both elems share each weight read ----
    float4 A0 = make_float4(0.f,0.f,0.f,0.f), A1 = make_float4(0.f,0.f,0.f,0.f);
    #pragma unroll
    for (int c = 0; c < 32; ++c) {
      float4 wv4 = WxT4[(c << 6) + l];
      float4 x0v = xu4[c];
      float4 x1v = xu4[33 + c];
      A0.x = fmaf(wv4.x, x0v.x, A0.x); A0.y = fmaf(wv4.y, x0v.y, A0.y);
      A0.z = fmaf(wv4.z, x0v.z, A0.z); A0.w = fmaf(wv4.w, x0v.w, A0.w);
      A1.x = fmaf(wv4.x, x1v.x, A1.x); A1.y = fmaf(wv4.y, x1v.y, A1.y);
      A1.z = fmaf(wv4.z, x1v.z, A1.z); A1.w = fmaf(wv4.w, x1v.w, A1.w);
    }
    float xn0 = (A0.x + A0.y) + (A0.z + A0.w);
    float xn1 = (A1.x + A1.y) + (A1.z + A1.w);
    xu[l]       = xn0;                             // x_t dead after X reads
    xu[132 + l] = xn1;
    // ---- Y: y_r = (Wy . [xn;w;u])_r for elem h ----
    float4 Y4 = make_float4(0.f, 0.f, 0.f, 0.f);
    #pragma unroll
    for (int c = 0; c < 32; ++c) {
      float4 wv4 = WyT4[(c << 5) + r];
      float4 xv = xu4[h*33 + c];
      Y4.x = fmaf(wv4.x, xv.x, Y4.x); Y4.y = fmaf(wv4.y, xv.y, Y4.y);
      Y4.z = fmaf(wv4.z, xv.z, Y4.z); Y4.w = fmaf(wv4.w, xv.w, Y4.w);
    }
    float y = (Y4.x + Y4.y) + (Y4.z + Y4.w);
    oG[t*32 + r] = y;                              // contiguous 128 B per half
    xu[h*132 + 96 + r] = unext;                    // after Y consumed u_t
  }
}

// ================= launch =================
extern "C" void kernel_launch(void* const* d_in, const int* in_sizes, int n_in,
                              void* d_out, int out_size, void* d_ws, size_t ws_size,
                              hipStream_t stream)
{
  const float* u_in = (const float*)d_in[0];
  const float* x0   = (const float*)d_in[1];
  const float* X    = (const float*)d_in[2];
  const float* Y    = (const float*)d_in[3];
  const float* B2   = (const float*)d_in[4];
  const float* C2   = (const float*)d_in[5];
  const float* D12  = (const float*)d_in[6];
  const float* L    = (const float*)d_in[7];   // D22_L
  const float* U    = (const float*)d_in[8];   // D22_U
  const float* D21  = (const float*)d_in[9];
  const float* gam  = (const float*)d_in[10];
  double* wsd = (double*)d_ws;
  float* out = (float*)d_out;

  hipLaunchKernelGGL(prep1, dim3(1), dim3(256), 0, stream, B2, C2, D12, L, U, D21, gam, wsd);
  hipLaunchKernelGGL(prep2, dim3(100), dim3(256), 0, stream, X, C2, D21, wsd);
  hipLaunchKernelGGL(prep3, dim3(1), dim3(256), 0, stream, Y, B2, C2, D12, D21, wsd);
  hipLaunchKernelGGL(ren_main, dim3(256), dim3(256), 0, stream, u_in, x0, wsd, out);
}

// Round 4
// 1545.262 us; speedup vs baseline: 1.8371x; 1.1271x over previous
//
#include <hip/hip_runtime.h>
#include <math.h>

// ---------------- dims / constants ----------------
#define EPS_Q 1e-4
#define TOLC  1e-3

// ws layout: doubles first
#define OFF_D22   0        // [32][32]
#define OFF_RINV  1024     // [32][32]
#define OFF_VR    2048     // [160][32]
#define OFF_T1    7168     // [160][32]
#define OFF_H     12288    // [160][160]
#define OFF_E     37888    // [64][64]
#define OFF_EI    41984    // [64][64]
#define OFF_TMP   46080    // [64][64]
#define OFF_TMP2  50176    // [64][64]
#define D_END     54272    // doubles
// float blob after doubles (byte offset 434176, 16B aligned):
// F_WXT  = 0      : Wx k-major f4-transposed [32 chunks][64 rows][4] = 8192 floats
// F_WYT  = 8192   : Wy k-major f4-transposed [32 chunks][32 rows][4] = 4096 floats
// F_D11  = 12288  : [32][32] strictly-lower, pre-scaled by 1/Lam_i   = 1024
// F_WA   = 13312  : [32][96] rows [C1(64)|D12(32)] * (1/Lam_r)        = 3072

// ================= prep 1: D22, R_cal^-1, vec_r, T1 =================
__global__ __launch_bounds__(256, 1) void prep1(
    const float* __restrict__ B2, const float* __restrict__ C2,
    const float* __restrict__ D12, const float* __restrict__ L,
    const float* __restrict__ U, const float* __restrict__ D21,
    const float* __restrict__ gam, double* __restrict__ wsd)
{
  __shared__ double aug[32][65];
  __shared__ double sFac[32];
  __shared__ int sPiv;
  const int tid = threadIdx.x;
  const double g = (double)gam[0];
  double* D22d = wsd + OFF_D22;

  for (int idx = tid; idx < 1024; idx += 256) {
    int i = idx >> 5, j = idx & 31;
    double s = (i == j) ? (g + 1.0) : 0.0;
    for (int k = 0; k < 32; ++k) s += (double)L[k*32+i] * (double)L[k*32+j];
    s += (double)U[i*32+j] - (double)U[j*32+i];
    D22d[idx] = s;
  }
  __syncthreads();
  for (int idx = tid; idx < 1024; idx += 256) {
    int i = idx >> 5, j = idx & 31;
    double s = (i == j) ? (-2.0 * g) : 0.0;
    s += D22d[i*32+j] + D22d[j*32+i];
    double q = 0.0;
    for (int k = 0; k < 32; ++k) q += D22d[k*32+i] * D22d[k*32+j];
    aug[i][j] = s - EPS_Q * q;
    aug[i][32+j] = (i == j) ? 1.0 : 0.0;
  }
  __syncthreads();
  for (int k = 0; k < 32; ++k) {
    if (tid < 64) {
      float mv = -1.f; int mi = k;
      if (tid < 32 && tid >= k) { mv = (float)fabs(aug[tid][k]); mi = tid; }
      #pragma unroll
      for (int o = 32; o; o >>= 1) {
        float ov = __shfl_xor(mv, o); int oi = __shfl_xor(mi, o);
        if (ov > mv) { mv = ov; mi = oi; }
      }
      if (tid == 0) sPiv = mi;
    }
    __syncthreads();
    int p = sPiv;
    if (p != k) for (int c = tid; c < 64; c += 256) { double t1 = aug[k][c]; aug[k][c] = aug[p][c]; aug[p][c] = t1; }
    __syncthreads();
    double pinv = 1.0 / aug[k][k];
    if (tid < 32 && tid != k) sFac[tid] = aug[tid][k];
    __syncthreads();
    for (int c = tid; c < 64; c += 256) aug[k][c] *= pinv;
    __syncthreads();
    for (int idx = tid; idx < 2048; idx += 256) {
      int r = idx >> 6, c = idx & 63;
      if (r != k) aug[r][c] -= sFac[r] * aug[k][c];
    }
    __syncthreads();
  }
  double* Rinv = wsd + OFF_RINV;
  for (int idx = tid; idx < 1024; idx += 256) Rinv[idx] = aug[idx >> 5][32 + (idx & 31)];

  double* vr = wsd + OFF_VR;
  for (int idx = tid; idx < 64*32; idx += 256) {
    int p = idx >> 5, k = idx & 31;
    double q = 0.0;
    for (int m = 0; m < 32; ++m) q += D22d[m*32+k] * (double)C2[m*64+p];
    vr[p*32+k] = (double)C2[k*64+p] - EPS_Q * q;
  }
  for (int idx = tid; idx < 32*32; idx += 256) {
    int p = idx >> 5, k = idx & 31;
    double q = 0.0;
    for (int m = 0; m < 32; ++m) q += D22d[m*32+k] * (double)D21[m*32+p];
    vr[(64+p)*32+k] = (double)D21[k*32+p] - EPS_Q * q - (double)D12[p*32+k];
  }
  for (int idx = tid; idx < 64*32; idx += 256) {
    int p = idx >> 5, k = idx & 31;
    vr[(96+p)*32+k] = (double)B2[p*32+k];
  }
  __syncthreads();
  double* T1 = wsd + OFF_T1;
  for (int idx = tid; idx < 160*32; idx += 256) {
    int p = idx >> 5, k2 = idx & 31;
    double s = 0.0;
    for (int k = 0; k < 32; ++k) s += vr[p*32+k] * Rinv[k*32+k2];
    T1[idx] = s;
  }
}

// ================= prep 2: H = X^T X + tol I + psi_r - psi_q =================
__global__ __launch_bounds__(256, 1) void prep2(
    const float* __restrict__ X, const float* __restrict__ C2,
    const float* __restrict__ D21, double* __restrict__ wsd)
{
  const double* vr = wsd + OFF_VR;
  const double* T1 = wsd + OFF_T1;
  double* H = wsd + OFF_H;
  int bi = blockIdx.x / 10, bj = blockIdx.x % 10;
  int i = bi*16 + (threadIdx.x >> 4);
  int j = bj*16 + (threadIdx.x & 15);
  double s = (i == j) ? TOLC : 0.0;
  for (int k = 0; k < 160; ++k) s += (double)X[k*160+i] * (double)X[k*160+j];
  double pr = 0.0;
  for (int k = 0; k < 32; ++k) pr += T1[i*32+k] * vr[j*32+k];
  s += pr;
  if (i < 96 && j < 96) {
    double vq = 0.0;
    for (int k = 0; k < 32; ++k) {
      double a = (i < 64) ? (double)C2[k*64+i] : (double)D21[k*32+(i-64)];
      double b = (j < 64) ? (double)C2[k*64+j] : (double)D21[k*32+(j-64)];
      vq += a*b;
    }
    s += EPS_Q * vq;
  }
  H[i*160+j] = s;
}

// ================= prep 3: E^-1 (GJ fp32 + 2x fp64 Newton), weight blob =================
__global__ __launch_bounds__(256, 1) void prep3(
    const float* __restrict__ Y, const float* __restrict__ B2,
    const float* __restrict__ C2, const float* __restrict__ D12,
    const float* __restrict__ D21, double* __restrict__ wsd)
{
  __shared__ float aug[64][130];
  __shared__ float sFac[64];
  __shared__ int sPiv;
  const int tid = threadIdx.x;
  double* H   = wsd + OFF_H;
  double* Ed  = wsd + OFF_E;
  double* Ei  = wsd + OFF_EI;
  double* Tm  = wsd + OFF_TMP;
  double* Tm2 = wsd + OFF_TMP2;
  double* D22d = wsd + OFF_D22;
  float* fb = (float*)(wsd + D_END);

  for (int idx = tid; idx < 4096; idx += 256) {
    int i = idx >> 6, j = idx & 63;
    double e = 0.5*(H[i*160+j] + H[(96+i)*160+(96+j)] + (double)Y[i*64+j] - (double)Y[j*64+i]);
    Ed[idx] = e;
    aug[i][j] = (float)e;
    aug[i][64+j] = (i == j) ? 1.f : 0.f;
  }
  __syncthreads();
  for (int k = 0; k < 64; ++k) {
    if (tid < 64) {
      float mv = -1.f; int mi = k;
      if (tid >= k) { mv = fabsf(aug[tid][k]); mi = tid; }
      #pragma unroll
      for (int o = 32; o; o >>= 1) {
        float ov = __shfl_xor(mv, o); int oi = __shfl_xor(mi, o);
        if (ov > mv) { mv = ov; mi = oi; }
      }
      if (tid == 0) sPiv = mi;
    }
    __syncthreads();
    int p = sPiv;
    if (p != k) for (int c = tid; c < 128; c += 256) { float t1 = aug[k][c]; aug[k][c] = aug[p][c]; aug[p][c] = t1; }
    __syncthreads();
    float pinv = 1.0f / aug[k][k];
    if (tid < 64 && tid != k) sFac[tid] = aug[tid][k];
    __syncthreads();
    for (int c = tid; c < 128; c += 256) aug[k][c] *= pinv;
    __syncthreads();
    for (int idx = tid; idx < 64*128; idx += 256) {
      int r = idx >> 7, c = idx & 127;
      if (r != k) aug[r][c] -= sFac[r] * aug[k][c];
    }
    __syncthreads();
  }
  for (int idx = tid; idx < 4096; idx += 256) Ei[idx] = (double)aug[idx >> 6][64 + (idx & 63)];
  __syncthreads();
  for (int it = 0; it < 2; ++it) {
    for (int idx = tid; idx < 4096; idx += 256) {
      int i = idx >> 6, j = idx & 63;
      double s = (i == j) ? 2.0 : 0.0;
      for (int k = 0; k < 64; ++k) s -= Ed[i*64+k] * Ei[k*64+j];
      Tm[idx] = s;
    }
    __syncthreads();
    for (int idx = tid; idx < 4096; idx += 256) {
      int i = idx >> 6, j = idx & 63;
      double s = 0.0;
      for (int k = 0; k < 64; ++k) s += Ei[i*64+k] * Tm[k*64+j];
      Tm2[idx] = s;
    }
    __syncthreads();
    for (int idx = tid; idx < 4096; idx += 256) Ei[idx] = Tm2[idx];
    __syncthreads();
  }
  // WxT: k-major f4-transposed [32 chunks][64 rows][4]
  for (int idx = tid; idx < 64*128; idx += 256) {
    int r = idx >> 7, col = idx & 127;
    double s = 0.0;
    if (col < 64)       { for (int k = 0; k < 64; ++k) s += Ei[r*64+k] * H[(96+k)*160 + col]; }
    else if (col < 96)  { int jj = col-64; for (int k = 0; k < 64; ++k) s += Ei[r*64+k] * H[(96+k)*160 + 64 + jj]; }
    else                { int jj = col-96; for (int k = 0; k < 64; ++k) s += Ei[r*64+k] * (double)B2[k*32+jj]; }
    fb[((col >> 2)*64 + r)*4 + (col & 3)] = (float)s;
  }
  // WyT: k-major f4-transposed [32 chunks][32 rows][4]; cols [C2(64)|D21(32)|D22(32)]
  for (int idx = tid; idx < 32*128; idx += 256) {
    int r = idx >> 7, col = idx & 127;
    float v;
    if (col < 64)      v = C2[r*64 + col];
    else if (col < 96) v = D21[r*32 + (col-64)];
    else               v = (float)D22d[r*32 + (col-96)];
    fb[8192 + ((col >> 2)*32 + r)*4 + (col & 3)] = v;
  }
  // D11' (strict lower, scaled by 1/Lam_i) @ 12288
  for (int idx = tid; idx < 1024; idx += 256) {
    int i = idx >> 5, j = idx & 31;
    double li = 2.0 / H[(64+i)*160 + 64+i];
    fb[12288 + idx] = (j < i) ? (float)(-H[(64+i)*160 + 64+j] * li) : 0.f;
  }
  // Wa = [C1 | D12] * (1/Lam_r), row-major [32][96] @ 13312
  for (int idx = tid; idx < 32*96; idx += 256) {
    int r = idx / 96, j = idx % 96;
    double li = 2.0 / H[(64+r)*160 + 64+r];
    double v = (j < 64) ? (-H[(64+r)*160 + j] * li) : ((double)D12[r*32 + (j-64)] * li);
    fb[13312 + idx] = (float)v;
  }
}

// ================= main recurrence =================
__device__ __forceinline__ float frcp(float x) {
#if __has_builtin(__builtin_amdgcn_rcpf)
  return __builtin_amdgcn_rcpf(x);
#else
  return 1.0f / x;
#endif
}
__device__ __forceinline__ float ftanh(float x) {
  float xc = fminf(fmaxf(x, -15.f), 15.f);
  float E = __builtin_exp2f(xc * 2.8853900817779268f);  // e^{2x}
  return 1.f - 2.f * frcp(E + 1.f);
}
__device__ __forceinline__ float hsum4(float4 a) { return (a.x + a.y) + (a.z + a.w); }

// block = 256 threads = 4 waves; each WAVE owns ONE element.
// grid = 512 blocks -> 2 blocks/CU (LDS 51.3 KB), 8 waves/CU = 2 waves/SIMD:
// the second wave per SIMD hides the serial tanh-chain + LDS latencies.
// No __syncthreads in the t-loop (all communication wave-internal).
__global__ __launch_bounds__(256, 2) void ren_main(
    const float* __restrict__ u_in, const float* __restrict__ x0,
    const double* __restrict__ wsd, float* __restrict__ out)
{
  __shared__ __align__(16) float sW[12288];    // WxT [32][64]f4 | WyT [32][32]f4
  __shared__ __align__(16) float sXU[4][132];  // per wave: x(64)|w(32)|u(32)|pad(4)
  const float* fb = (const float*)(wsd + D_END);
  const int tid = threadIdx.x;
  {
    const float4* g4 = (const float4*)fb;
    float4* s4 = (float4*)sW;
    for (int i = tid; i < 3072; i += 256) s4[i] = g4[i];
  }
  const int wv = tid >> 6, l = tid & 63;
  const int r = l & 31, lh = l >> 5;
  const int e = blockIdx.x * 4 + wv;           // this wave's element
  float* xu = &sXU[wv][0];
  // Wa half-row in registers: 12 f4 per lane (half lh of row r)
  float4 wa[12];
  {
    const float4* WaG = (const float4*)(fb + 13312);
    #pragma unroll
    for (int c = 0; c < 12; ++c) wa[c] = WaG[r*24 + lh*12 + c];
  }
  float d11[32];
  {
    const float4* DG = (const float4*)(fb + 12288);
    #pragma unroll
    for (int c = 0; c < 8; ++c) {
      float4 dv = DG[r*8 + c];
      d11[4*c+0] = dv.x; d11[4*c+1] = dv.y; d11[4*c+2] = dv.z; d11[4*c+3] = dv.w;
    }
  }
  // x0 and u(t=0)
  xu[l] = x0[(size_t)e*64 + l];
  xu[96 + r] = u_in[(size_t)e*8192 + r];       // both halves write same value
  __syncthreads();   // weights staged (once, outside t-loop)
  const float4* xu4  = (const float4*)xu;      // 33 f4: x 0-15 | w 16-23 | u 24-31
  const float4* WxT4 = (const float4*)sW;
  const float4* WyT4 = (const float4*)(sW + 8192);
  const float* uG = u_in + (size_t)e * 8192;
  float* oG = out + (size_t)e * 8192;

  for (int t = 0; t < 256; ++t) {
    const int tn = (t < 255) ? (t + 1) : 255;
    float unext = uG[tn*32 + r];               // prefetch u_{t+1}
    // ---- A: a_r, k-split across halves, combine via shfl ----
    float4 s4 = make_float4(0.f, 0.f, 0.f, 0.f);
    #pragma unroll
    for (int c = 0; c < 12; ++c) {
      int ch = lh*12 + c;
      int xi = (ch < 16) ? ch : (ch + 8);      // u chunks at f4 24..31
      float4 xv = xu4[xi]; float4 wv4 = wa[c];
      s4.x = fmaf(wv4.x, xv.x, s4.x); s4.y = fmaf(wv4.y, xv.y, s4.y);
      s4.z = fmaf(wv4.z, xv.z, s4.z); s4.w = fmaf(wv4.w, xv.w, s4.w);
    }
    float a = hsum4(s4);
    a += __shfl_xor(a, 32);                    // all 64 lanes: a for row r
    // ---- X partial: A1.x + A3.u (independent of chain; scheduler filler) ----
    float4 P4 = make_float4(0.f, 0.f, 0.f, 0.f);
    #pragma unroll
    for (int c = 0; c < 16; ++c) {
      float4 wv4 = WxT4[(c << 6) + l]; float4 xv = xu4[c];
      P4.x = fmaf(wv4.x, xv.x, P4.x); P4.y = fmaf(wv4.y, xv.y, P4.y);
      P4.z = fmaf(wv4.z, xv.z, P4.z); P4.w = fmaf(wv4.w, xv.w, P4.w);
    }
    #pragma unroll
    for (int c = 24; c < 32; ++c) {
      float4 wv4 = WxT4[(c << 6) + l]; float4 xv = xu4[c];
      P4.x = fmaf(wv4.x, xv.x, P4.x); P4.y = fmaf(wv4.y, xv.y, P4.y);
      P4.z = fmaf(wv4.z, xv.z, P4.z); P4.w = fmaf(wv4.w, xv.w, P4.w);
    }
    // ---- Y partial: D22.u chunks (lh0: 24..27, lh1: 28..31) ----
    float4 Q4 = make_float4(0.f, 0.f, 0.f, 0.f);
    #pragma unroll
    for (int c = 0; c < 4; ++c) {
      int ch = 24 + lh*4 + c;
      float4 wv4 = WyT4[(ch << 5) + r]; float4 xv = xu4[ch];
      Q4.x = fmaf(wv4.x, xv.x, Q4.x); Q4.y = fmaf(wv4.y, xv.y, Q4.y);
      Q4.z = fmaf(wv4.z, xv.z, Q4.z); Q4.w = fmaf(wv4.w, xv.w, Q4.w);
    }
    // ---- serial tanh forward-substitution (readlane broadcast) ----
    float v = a;
    #pragma unroll
    for (int j = 0; j < 31; ++j) {
      float tt = ftanh(v);
      float b = __int_as_float(__builtin_amdgcn_readlane(__float_as_int(tt), j));
      v = fmaf(d11[j], b, v);
    }
    float myw = ftanh(v);
    xu[64 + r] = myw;                          // both halves same value
    // ---- X final: A2.w (chunks 16..23), then store xn ----
    #pragma unroll
    for (int c = 16; c < 24; ++c) {
      float4 wv4 = WxT4[(c << 6) + l]; float4 xv = xu4[c];
      P4.x = fmaf(wv4.x, xv.x, P4.x); P4.y = fmaf(wv4.y, xv.y, P4.y);
      P4.z = fmaf(wv4.z, xv.z, P4.z); P4.w = fmaf(wv4.w, xv.w, P4.w);
    }
    xu[l] = hsum4(P4);                         // xn row l
    // ---- Y final: chunks lh*12 .. lh*12+11 (xn + w), combine via shfl ----
    #pragma unroll
    for (int c = 0; c < 12; ++c) {
      int ch = lh*12 + c;
      float4 wv4 = WyT4[(ch << 5) + r]; float4 xv = xu4[ch];
      Q4.x = fmaf(wv4.x, xv.x, Q4.x); Q4.y = fmaf(wv4.y, xv.y, Q4.y);
      Q4.z = fmaf(wv4.z, xv.z, Q4.z); Q4.w = fmaf(wv4.w, xv.w, Q4.w);
    }
    float y = hsum4(Q4);
    y += __shfl_xor(y, 32);
    if (l < 32) oG[t*32 + l] = y;              // contiguous 128 B
    xu[96 + r] = unext;                        // u_{t+1} (u_t fully consumed)
  }
}

// ================= launch =================
extern "C" void kernel_launch(void* const* d_in, const int* in_sizes, int n_in,
                              void* d_out, int out_size, void* d_ws, size_t ws_size,
                              hipStream_t stream)
{
  const float* u_in = (const float*)d_in[0];
  const float* x0   = (const float*)d_in[1];
  const float* X    = (const float*)d_in[2];
  const float* Y    = (const float*)d_in[3];
  const float* B2   = (const float*)d_in[4];
  const float* C2   = (const float*)d_in[5];
  const float* D12  = (const float*)d_in[6];
  const float* L    = (const float*)d_in[7];   // D22_L
  const float* U    = (const float*)d_in[8];   // D22_U
  const float* D21  = (const float*)d_in[9];
  const float* gam  = (const float*)d_in[10];
  double* wsd = (double*)d_ws;
  float* out = (float*)d_out;

  hipLaunchKernelGGL(prep1, dim3(1), dim3(256), 0, stream, B2, C2, D12, L, U, D21, gam, wsd);
  hipLaunchKernelGGL(prep2, dim3(100), dim3(256), 0, stream, X, C2, D21, wsd);
  hipLaunchKernelGGL(prep3, dim3(1), dim3(256), 0, stream, Y, B2, C2, D12, D21, wsd);
  hipLaunchKernelGGL(ren_main, dim3(512), dim3(256), 0, stream, u_in, x0, wsd, out);
}